// Round 3
// baseline (494.832 us; speedup 1.0000x reference)
//
#include <hip/hip_runtime.h>
#include <stdint.h>

typedef _Float16 f16_t;
typedef _Float16 f16x4 __attribute__((ext_vector_type(4)));
typedef _Float16 f16x8 __attribute__((ext_vector_type(8)));
typedef float f32x4 __attribute__((ext_vector_type(4)));

// ---------------------------------------------------------------------------
// async global->LDS, 16B per lane. LDS dest is wave-uniform base + lane*16.
// ---------------------------------------------------------------------------
__device__ __forceinline__ void async16(const void* g, void* lds) {
    typedef __attribute__((address_space(3))) void lds_void;
    typedef __attribute__((address_space(1))) void glb_void;
    lds_void* l = (lds_void*)(unsigned int)(unsigned long long)lds;
    glb_void* gp = (glb_void*)(unsigned long long)g;
    __builtin_amdgcn_global_load_lds(gp, l, 16, 0, 0);
}

// ---------------------------------------------------------------------------
// fp32 -> fp16, three arrays in one dispatch (weights)
// ---------------------------------------------------------------------------
__global__ void cvt3_f32_f16(const float* __restrict__ a, const float* __restrict__ b,
                             const float* __restrict__ c,
                             f16_t* __restrict__ oa, f16_t* __restrict__ ob,
                             f16_t* __restrict__ oc, int na, int nb, int nc) {
    int i = blockIdx.x * 256 + threadIdx.x;
    if (i < na) { oa[i] = (f16_t)a[i]; return; }
    i -= na;
    if (i < nb) { ob[i] = (f16_t)b[i]; return; }
    i -= nb;
    if (i < nc) { oc[i] = (f16_t)c[i]; }
}

// ---------------------------------------------------------------------------
// Transpose + convert to fp16.  in: [R][S] per batch  ->  out: [S][R]
// ---------------------------------------------------------------------------
template <typename TIN>
__global__ void transpose_cvt(const TIN* __restrict__ in, f16_t* __restrict__ out,
                              int R, int S, long long inStride, long long outStride) {
    __shared__ float tile[32][33];
    const int b = blockIdx.z;
    const TIN* ip = in + (long long)b * inStride;
    f16_t* op = out + (long long)b * outStride;
    const int s0 = blockIdx.x * 32;
    const int r0 = blockIdx.y * 32;
    const int t = threadIdx.x;
    const int lr = t >> 3;
    const int lc = (t & 7) * 4;

    const TIN* src = ip + (long long)(r0 + lr) * S + s0 + lc;
    float v0, v1, v2, v3;
    if (sizeof(TIN) == 4) {
        float4 v = *(const float4*)src;
        v0 = v.x; v1 = v.y; v2 = v.z; v3 = v.w;
    } else {
        f16x4 v = *(const f16x4*)src;
        v0 = (float)v[0]; v1 = (float)v[1]; v2 = (float)v[2]; v3 = (float)v[3];
    }
    tile[lr][lc + 0] = v0;
    tile[lr][lc + 1] = v1;
    tile[lr][lc + 2] = v2;
    tile[lr][lc + 3] = v3;
    __syncthreads();

    const int sr = t >> 3;
    const int rc = (t & 7) * 4;
    f16x4 o;
    o[0] = (f16_t)tile[rc + 0][sr];
    o[1] = (f16_t)tile[rc + 1][sr];
    o[2] = (f16_t)tile[rc + 2][sr];
    o[3] = (f16_t)tile[rc + 3][sr];
    *(f16x4*)(op + (long long)(s0 + sr) * R + r0 + rc) = o;
}

// ---------------------------------------------------------------------------
// bt-GEMM:  C[m,n] = sum_k A[m,k] * Bt[n,k]     (both K-contiguous, fp16)
// Swapped-operand MFMA: mfma(bfr, af) -> lane holds 4 consecutive COLUMNS of C
//   => vectorized epilogue (f16x4 / f32x4 stores).
// KSPLIT>1: blockIdx.z encodes (batch, slice); partial fp32 outputs at
//   C + s*strideCs, summed later.
// MODE 0: f16 C.  MODE 1: fp32 C.  MODE 2: f16 gamma*acc + resid.
// ---------------------------------------------------------------------------
template <int BM, int BN, int TM, int TN, int WN, int MODE, int KSPLIT>
__global__ __launch_bounds__(256, 2)
void gemm_bt(const f16_t* __restrict__ A, const f16_t* __restrict__ B,
             void* __restrict__ C, const f16_t* __restrict__ resid,
             const float* __restrict__ gamma,
             int ldc, int K, int lda, int ldb,
             long long strideA, long long strideB, long long strideC,
             long long strideCs) {
    constexpr int BK = 32;
    __shared__ __align__(16) f16_t As[BM * BK];
    __shared__ __align__(16) f16_t Bs[BN * BK];

    const int tid = threadIdx.x;
    const int wave = tid >> 6;
    const int lane = tid & 63;
    const int wm = wave / WN;
    const int wn = wave % WN;
    const int l16 = lane & 15;
    const int l4 = lane >> 4;

    const int zs = blockIdx.z;
    const int zb = zs / KSPLIT;
    const int sp = zs % KSPLIT;
    const long long kOff = (long long)sp * K;

    const f16_t* Ab = A + (long long)zb * strideA + (long long)blockIdx.y * BM * lda + kOff;
    const f16_t* Bb = B + (long long)zb * strideB + (long long)blockIdx.x * BN * ldb + kOff;

    f32x4 zero = {0.f, 0.f, 0.f, 0.f};
    f32x4 acc[TM][TN];
#pragma unroll
    for (int i = 0; i < TM; ++i)
#pragma unroll
        for (int j = 0; j < TN; ++j) acc[i][j] = zero;

    for (int k0 = 0; k0 < K; k0 += BK) {
#pragma unroll
        for (int r = 0; r < (BM * 4) / 256; ++r) {
            int seg = r * 256 + tid;
            const f16_t* g = Ab + (long long)(seg >> 2) * lda + k0 + (seg & 3) * 8;
            async16(g, &As[(r * 256 + wave * 64) * 8]);
        }
#pragma unroll
        for (int r = 0; r < (BN * 4) / 256; ++r) {
            int seg = r * 256 + tid;
            const f16_t* g = Bb + (long long)(seg >> 2) * ldb + k0 + (seg & 3) * 8;
            async16(g, &Bs[(r * 256 + wave * 64) * 8]);
        }
        __syncthreads();

        f16x8 af[TM], bfr[TN];
#pragma unroll
        for (int i = 0; i < TM; ++i)
            af[i] = *(const f16x8*)&As[((wm * TM + i) * 16 + l16) * BK + l4 * 8];
#pragma unroll
        for (int j = 0; j < TN; ++j)
            bfr[j] = *(const f16x8*)&Bs[((wn * TN + j) * 16 + l16) * BK + l4 * 8];
#pragma unroll
        for (int i = 0; i < TM; ++i)
#pragma unroll
            for (int j = 0; j < TN; ++j)
                acc[i][j] = __builtin_amdgcn_mfma_f32_16x16x32_f16(bfr[j], af[i], acc[i][j], 0, 0, 0);
        __syncthreads();
    }

    // swapped layout: lane holds C[row0+i*16+l16, col0+j*16+l4*4 + r], r=0..3
    const int row0 = blockIdx.y * BM + wm * TM * 16;
    const int col0 = blockIdx.x * BN + wn * TN * 16;
    const float g = (MODE == 2) ? gamma[0] : 0.f;
    const long long cBase = (long long)zb * strideC + (long long)sp * strideCs;
#pragma unroll
    for (int i = 0; i < TM; ++i) {
        const int row = row0 + i * 16 + l16;
#pragma unroll
        for (int j = 0; j < TN; ++j) {
            const int col = col0 + j * 16 + l4 * 4;
            const long long idx = cBase + (long long)row * ldc + col;
            if (MODE == 1) {
                *(f32x4*)((float*)C + idx) = acc[i][j];
            } else if (MODE == 0) {
                f16x4 o;
#pragma unroll
                for (int r = 0; r < 4; ++r) o[r] = (f16_t)acc[i][j][r];
                *(f16x4*)((f16_t*)C + idx) = o;
            } else {
                const f16x4 rv = *(const f16x4*)(resid + idx);
                f16x4 o;
#pragma unroll
                for (int r = 0; r < 4; ++r) o[r] = (f16_t)(g * acc[i][j][r] + (float)rv[r]);
                *(f16x4*)((f16_t*)C + idx) = o;
            }
        }
    }
}

// ---------------------------------------------------------------------------
// sum 4 split-K partials + softmax over rows of 256 fp32 -> fp16.
// One wave per row, 4 rows per block. part layout: [s][b][c][d] fp32.
// ---------------------------------------------------------------------------
__global__ void softmax256(const float* __restrict__ part, f16_t* __restrict__ out) {
    const int row = blockIdx.x * 4 + (threadIdx.x >> 6);  // [0, B*C)
    const int lane = threadIdx.x & 63;
    const long long base = (long long)row * 256 + lane * 4;
    float4 v = *(const float4*)(part + base);
#pragma unroll
    for (int s = 1; s < 4; ++s) {
        const float4 p = *(const float4*)(part + (long long)s * 1048576 + base);
        v.x += p.x; v.y += p.y; v.z += p.z; v.w += p.w;
    }
    float m = fmaxf(fmaxf(v.x, v.y), fmaxf(v.z, v.w));
#pragma unroll
    for (int off = 32; off > 0; off >>= 1) m = fmaxf(m, __shfl_xor(m, off, 64));
    float e0 = __expf(v.x - m), e1 = __expf(v.y - m);
    float e2 = __expf(v.z - m), e3 = __expf(v.w - m);
    float s = e0 + e1 + e2 + e3;
#pragma unroll
    for (int off = 32; off > 0; off >>= 1) s += __shfl_xor(s, off, 64);
    const float inv = 1.0f / s;
    f16x4 o;
    o[0] = (f16_t)(e0 * inv);
    o[1] = (f16_t)(e1 * inv);
    o[2] = (f16_t)(e2 * inv);
    o[3] = (f16_t)(e3 * inv);
    *(f16x4*)(out + (long long)row * 256 + lane * 4) = o;
}

// ---------------------------------------------------------------------------
// Orchestration
// ---------------------------------------------------------------------------
extern "C" void kernel_launch(void* const* d_in, const int* in_sizes, int n_in,
                              void* d_out, int out_size, void* d_ws, size_t ws_size,
                              hipStream_t stream) {
    (void)in_sizes; (void)n_in; (void)out_size; (void)ws_size;

    const float* x1 = (const float*)d_in[0];     // [16,512,64,64]
    const float* x2 = (const float*)d_in[1];     // [16,320,64,64]
    const float* w_img = (const float*)d_in[2];  // [256,512]
    const float* w_txt = (const float*)d_in[3];  // [256,320]
    const float* w_out = (const float*)d_in[4];  // [512,256]
    const float* gamma = (const float*)d_in[5];  // [1]

    constexpr int B = 16, C1 = 512, C2 = 320, C = 256, N = 4096, OC = 512;

    // ws layout (bytes): ~104.7 MiB
    char* ws = (char*)d_ws;
    f16_t* wib = (f16_t*)(ws + 0);          // 256*512*2
    f16_t* wtb = (f16_t*)(ws + 262144);     // 256*320*2
    f16_t* wob = (f16_t*)(ws + 425984);     // 512*256*2
    f16_t* img = (f16_t*)(ws + 688128);     // 16*256*4096*2 = 33554432
    f16_t* x2t = (f16_t*)(ws + 34242560);   // 16*4096*320*2 = 41943040
    f16_t* kvT = x2t;                       // reuse (x2t dead after GEMM2)
    f16_t* yT  = (f16_t*)(ws + 76185600);   // 33554432 -> ends 109740032

    // d_out used as scratch; final GEMM overwrites all 134 MB
    char* oc = (char*)d_out;
    f16_t* x1t   = (f16_t*)(oc);              // [0, 67108864)
    f16_t* kv    = (f16_t*)(oc);              // [0, 33554432)  after x1t dead
    f16_t* y     = (f16_t*)(oc + 67108864);   // 33554432
    float* attnp = (float*)(oc + 100663296);  // 4*16*256*256*4 = 16777216
    f16_t* attns = (f16_t*)(oc + 117440512);  // 2097152 -> ends 119537664

    // 1. weights -> f16 (single dispatch)
    {
        const int na = C * C1, nb = C * C2, nc = OC * C;
        cvt3_f32_f16<<<(na + nb + nc + 255) / 256, 256, 0, stream>>>(
            w_img, w_txt, w_out, wib, wtb, wob, na, nb, nc);
    }

    // 2. x1 [C1,N] -> x1t [N,C1] f16 ; x2 -> x2t [N,C2]
    transpose_cvt<float><<<dim3(N / 32, C1 / 32, B), 256, 0, stream>>>(
        x1, x1t, C1, N, (long long)C1 * N, (long long)N * C1);
    transpose_cvt<float><<<dim3(N / 32, C2 / 32, B), 256, 0, stream>>>(
        x2, x2t, C2, N, (long long)C2 * N, (long long)N * C2);

    // 3. img = w_img * x1 -> [C,N] f16   (M=256,N=4096,K=512)
    gemm_bt<128, 128, 4, 4, 2, 0, 1><<<dim3(N / 128, C / 128, B), 256, 0, stream>>>(
        wib, x1t, img, nullptr, nullptr, N, C1, C1, C1,
        0LL, (long long)N * C1, (long long)C * N, 0LL);

    // 4. kv = w_txt * x2 -> [C,N] f16    (M=256,N=4096,K=320)
    gemm_bt<128, 128, 4, 4, 2, 0, 1><<<dim3(N / 128, C / 128, B), 256, 0, stream>>>(
        wtb, x2t, kv, nullptr, nullptr, N, C2, C2, C2,
        0LL, (long long)N * C2, (long long)C * N, 0LL);

    // 5. kvT [N,C]
    transpose_cvt<f16_t><<<dim3(N / 32, C / 32, B), 256, 0, stream>>>(
        kv, kvT, C, N, (long long)C * N, (long long)N * C);

    // 6. attn partials = img * kv^T, split-K x4  [4][B,C,C] fp32
    gemm_bt<64, 64, 2, 2, 2, 1, 4><<<dim3(C / 64, C / 64, B * 4), 256, 0, stream>>>(
        img, kv, attnp, nullptr, nullptr, C, N / 4, N, N,
        (long long)C * N, (long long)C * N, (long long)C * C, (long long)B * C * C);

    // 7. sum partials + softmax -> f16
    softmax256<<<(B * C) / 4, 256, 0, stream>>>(attnp, attns);

    // 8. y = gamma * (attn * kv) + img -> [C,N] f16  (M=256,N=4096,K=256)
    gemm_bt<128, 128, 4, 4, 2, 2, 1><<<dim3(N / 128, C / 128, B), 256, 0, stream>>>(
        attns, kvT, y, img, gamma, N, C, C, C,
        (long long)C * C, (long long)N * C, (long long)C * N, 0LL);

    // 9. yT [N,C]
    transpose_cvt<f16_t><<<dim3(N / 32, C / 32, B), 256, 0, stream>>>(
        y, yT, C, N, (long long)C * N, (long long)N * C);

    // 10. out = w_out * y -> [OC,N] fp32  (M=512,N=4096,K=256)
    gemm_bt<128, 128, 4, 4, 2, 1, 1><<<dim3(N / 128, OC / 128, B), 256, 0, stream>>>(
        wob, yT, (float*)d_out, nullptr, nullptr, N, C, C, C,
        0LL, (long long)N * C, (long long)OC * N, 0LL);
}